// Round 8
// baseline (132.622 us; speedup 1.0000x reference)
//
#include <hip/hip_runtime.h>
#include <math.h>

#define N_NODES 2048
#define IN_F 128
#define OUT_F 32
#define NEG_INF -9e15f
#define KB 16      // k-chunks (split-k factor)
#define KC 128     // k per chunk
#define TI 8       // i rows per wave

// Swizzled column for the per-wave p buffer p_s[i][KC]: element k lives at
// column k ^ (((k>>4)&7)<<2). Conflict-free for both the phase-2 float2
// writes (k=2*lane) and phase-3 float4 broadcast reads (k=16*cp+4g).
__device__ __forceinline__ int pcol(int k) {
    return k ^ (((k >> 4) & 7) << 2);
}

// ---------------------------------------------------------------------------
// Kernel A: Wh1[N][32] = h @ W[:128], Wh2T[32][N] = (h @ W[128:])^T,
//           Q[k] = 0.6*sum_f a[f]*Wh2[k,f], C[f] = 0.4*a[f].
// (leakyrelu(x) = 0.6x + 0.4|x|; the per-row-i constant cancels in softmax.)
// ---------------------------------------------------------------------------
__global__ __launch_bounds__(256) void precompute_wh(
    const float* __restrict__ h, const float* __restrict__ W,
    const float* __restrict__ a,
    float* __restrict__ Wh1, float* __restrict__ Wh2T,
    float* __restrict__ Q, float* __restrict__ C)
{
    __shared__ float h_s[8][IN_F];
    __shared__ float tr[8][OUT_F];
    const int t = threadIdx.x;
    const int i0 = blockIdx.x * 8;

    ((float4*)&h_s[0][0])[t] = ((const float4*)(h + (size_t)i0 * IN_F))[t];
    __syncthreads();

    const int f = t & 31;
    const int r = t >> 5;
    float acc1 = 0.f, acc2 = 0.f;
    #pragma unroll 8
    for (int c = 0; c < IN_F; ++c) {
        const float hv = h_s[r][c];
        acc1 = fmaf(hv, W[c * OUT_F + f], acc1);
        acc2 = fmaf(hv, W[(IN_F + c) * OUT_F + f], acc2);
    }
    Wh1[(i0 + r) * OUT_F + f] = acc1;
    tr[r][f] = acc2;

    float q = 0.6f * a[f] * acc2;
    #pragma unroll
    for (int off = 16; off > 0; off >>= 1) q += __shfl_xor(q, off, 64);
    if (f == 0) Q[i0 + r] = q;
    if (blockIdx.x == 0 && t < OUT_F) C[t] = 0.4f * a[t];

    __syncthreads();
    const int f2 = t >> 3, r2 = t & 7;
    Wh2T[f2 * N_NODES + i0 + r2] = tr[r2][f2];
}

// ---------------------------------------------------------------------------
// Kernel B: 256-thread blocks = 4 INDEPENDENT waves; wave w of block b owns
// (i-tile = b>>2, k-chunk = (b&3)*4 + w). No __syncthreads anywhere: each
// wave uses its own LDS slice, and within-wave LDS write->read ordering is
// enforced by the compiler's lgkmcnt waits. This packs 4 waves per WG slot
// (R6's 4096 single-wave WGs sat at ~3 waves/CU: WG-slot limited, VALU 26%).
//   s[i,k] = Q[k] + sum_f C[f]*|Wh1[i,f]+Wh2[k,f]|, masked by adj.
//   Writes per chunk: m_c[i], l_c[i], o_c[i][32] (online-softmax partials).
// __launch_bounds__(256,2): VGPR cap = 256/min = 128 (R4/R5: min=4 -> 64-cap
// -> 330 MB scratch spill; R6: no cap -> 164 VGPR, no spill, but 3 waves/SIMD).
// ---------------------------------------------------------------------------
__global__ __launch_bounds__(256, 2) void gat_partial(
    const float* __restrict__ Wh1, const float* __restrict__ Wh2T,
    const float* __restrict__ Q, const float* __restrict__ C,
    const int* __restrict__ adj,
    float* __restrict__ m_ws, float* __restrict__ l_ws,
    float* __restrict__ o_ws)
{
    __shared__ __align__(16) float w1s_a[4][TI * OUT_F];   // 4 KB (1 KB/wave)
    __shared__ __align__(16) float p_s_a[4][TI * KC];      // 16 KB (4 KB/wave)

    const int t = threadIdx.x;
    const int lane = t & 63;
    const int wid = t >> 6;
    const int ib = blockIdx.x >> 2;
    const int cb = ((blockIdx.x & 3) << 2) | wid;
    const int i0 = ib * TI;
    const int kg = cb * KC + 2 * lane;               // global k of this pair

    float* __restrict__ w1s = w1s_a[wid];
    float* __restrict__ p_s = p_s_a[wid];

    // per-wave copy of the 8 Wh1 rows (64 lanes x float4 = exactly 1 KB)
    ((float4*)w1s)[lane] = ((const float4*)(Wh1 + (size_t)i0 * OUT_F))[lane];

    // prefetch adj + Q (HBM/L2 latency hides under the whole f-loop)
    int2 ad[TI];
    #pragma unroll
    for (int i = 0; i < TI; ++i)
        ad[i] = *(const int2*)(adj + (size_t)(i0 + i) * N_NODES + kg);
    const float2 q2 = *(const float2*)(Q + kg);

    // ---------------- Phase 1: scores ----------------
    float a0[TI], a1[TI];
    #pragma unroll
    for (int i = 0; i < TI; ++i) { a0[i] = 0.f; a1[i] = 0.f; }

    #pragma unroll
    for (int j = 0; j < 8; ++j) {
        float2 w2[4];
        #pragma unroll
        for (int e = 0; e < 4; ++e)
            w2[e] = *(const float2*)(Wh2T + (size_t)(4 * j + e) * N_NODES + kg);
        const float c0 = C[4 * j + 0], c1 = C[4 * j + 1];
        const float c2 = C[4 * j + 2], c3 = C[4 * j + 3];
        #pragma unroll
        for (int i = 0; i < TI; ++i) {
            const float4 w1 = *(const float4*)&w1s[i * OUT_F + 4 * j]; // LDS bcast
            float x;
            x = w1.x + w2[0].x; a0[i] = fmaf(c0, fabsf(x), a0[i]);
            x = w1.x + w2[0].y; a1[i] = fmaf(c0, fabsf(x), a1[i]);
            x = w1.y + w2[1].x; a0[i] = fmaf(c1, fabsf(x), a0[i]);
            x = w1.y + w2[1].y; a1[i] = fmaf(c1, fabsf(x), a1[i]);
            x = w1.z + w2[2].x; a0[i] = fmaf(c2, fabsf(x), a0[i]);
            x = w1.z + w2[2].y; a1[i] = fmaf(c2, fabsf(x), a1[i]);
            x = w1.w + w2[3].x; a0[i] = fmaf(c3, fabsf(x), a0[i]);
            x = w1.w + w2[3].y; a1[i] = fmaf(c3, fabsf(x), a1[i]);
        }
    }

    // ---------------- Phase 2: mask, local max, exp, local sum ----------------
    #pragma unroll
    for (int i = 0; i < TI; ++i) {
        const float s0 = (ad[i].x > 0) ? a0[i] + q2.x : NEG_INF;
        const float s1 = (ad[i].y > 0) ? a1[i] + q2.y : NEG_INF;
        float mm = fmaxf(s0, s1);
        #pragma unroll
        for (int off = 32; off > 0; off >>= 1)
            mm = fmaxf(mm, __shfl_xor(mm, off, 64));
        // gate masked entries: if the whole chunk is masked (mm == NEG_INF),
        // exp(s-mm) would be 1 — force p = 0 instead.
        const float p0 = (s0 > 0.5f * NEG_INF) ? __expf(s0 - mm) : 0.f;
        const float p1 = (s1 > 0.5f * NEG_INF) ? __expf(s1 - mm) : 0.f;
        float ll = p0 + p1;
        #pragma unroll
        for (int off = 32; off > 0; off >>= 1)
            ll += __shfl_xor(ll, off, 64);
        *(float2*)&p_s[i * KC + pcol(2 * lane)] = make_float2(p0, p1);
        if (lane == 0) {
            m_ws[(size_t)(i0 + i) * KB + cb] = mm;
            l_ws[(size_t)(i0 + i) * KB + cb] = ll;
        }
    }
    // no barrier: this wave wrote p_s and reads it back itself (lgkmcnt order)

    // ---------------- Phase 3: o_c = p @ Wh1 (chunk) ----------------
    const int fq = (lane & 7) * 4;   // f quad
    const int cp = lane >> 3;        // 8 sub-chunks of 16 k
    float4 av[TI];
    #pragma unroll
    for (int i = 0; i < TI; ++i) av[i] = make_float4(0.f, 0.f, 0.f, 0.f);

    #pragma unroll
    for (int g = 0; g < 4; ++g) {
        const int kl = 16 * cp + 4 * g;              // local k quad base
        float4 w[4];
        #pragma unroll
        for (int d = 0; d < 4; ++d)
            w[d] = *(const float4*)(Wh1 + (size_t)(cb * KC + kl + d) * OUT_F + fq);
        #pragma unroll
        for (int i = 0; i < TI; ++i) {
            const float4 pv = *(const float4*)&p_s[i * KC + pcol(kl)];
            av[i].x = fmaf(pv.x, w[0].x, av[i].x); av[i].y = fmaf(pv.x, w[0].y, av[i].y);
            av[i].z = fmaf(pv.x, w[0].z, av[i].z); av[i].w = fmaf(pv.x, w[0].w, av[i].w);
            av[i].x = fmaf(pv.y, w[1].x, av[i].x); av[i].y = fmaf(pv.y, w[1].y, av[i].y);
            av[i].z = fmaf(pv.y, w[1].z, av[i].z); av[i].w = fmaf(pv.y, w[1].w, av[i].w);
            av[i].x = fmaf(pv.z, w[2].x, av[i].x); av[i].y = fmaf(pv.z, w[2].y, av[i].y);
            av[i].z = fmaf(pv.z, w[2].z, av[i].z); av[i].w = fmaf(pv.z, w[2].w, av[i].w);
            av[i].x = fmaf(pv.w, w[3].x, av[i].x); av[i].y = fmaf(pv.w, w[3].y, av[i].y);
            av[i].z = fmaf(pv.w, w[3].z, av[i].z); av[i].w = fmaf(pv.w, w[3].w, av[i].w);
        }
    }

    // reduce over cp (lane bits 3-5)
    #pragma unroll
    for (int off = 8; off <= 32; off <<= 1) {
        #pragma unroll
        for (int i = 0; i < TI; ++i) {
            av[i].x += __shfl_xor(av[i].x, off, 64);
            av[i].y += __shfl_xor(av[i].y, off, 64);
            av[i].z += __shfl_xor(av[i].z, off, 64);
            av[i].w += __shfl_xor(av[i].w, off, 64);
        }
    }
    if (lane < 8) {                  // lane b writes f-quad 4b
        #pragma unroll
        for (int i = 0; i < TI; ++i)
            *(float4*)&o_ws[((size_t)(i0 + i) * KB + cb) * OUT_F + fq] = av[i];
    }
}

// ---------------------------------------------------------------------------
// Kernel C: combine the KB chunk partials per row:
//   M = max_c m_c;  w_c = e^{m_c - M};  L = sum_c l_c w_c;
//   out[i,f] = ELU( (sum_c o_c[i,f] w_c) / L ).
// Empty chunks: l_c = 0, m_c = NEG_INF -> w_c = 0.
// ---------------------------------------------------------------------------
__global__ __launch_bounds__(256) void gat_combine(
    const float* __restrict__ m_ws, const float* __restrict__ l_ws,
    const float* __restrict__ o_ws, float* __restrict__ out)
{
    const int g = blockIdx.x * 256 + threadIdx.x;    // 65536 = 2048*32
    const int i = g >> 5, f = g & 31;

    float mv[KB];
    float M = NEG_INF;
    #pragma unroll
    for (int c = 0; c < KB; ++c) {
        mv[c] = m_ws[(size_t)i * KB + c];
        M = fmaxf(M, mv[c]);
    }
    float L = 0.f, S = 0.f;
    #pragma unroll
    for (int c = 0; c < KB; ++c) {
        const float wc = __expf(mv[c] - M);
        L = fmaf(l_ws[(size_t)i * KB + c], wc, L);
        S = fmaf(o_ws[((size_t)i * KB + c) * OUT_F + f], wc, S);
    }
    const float val = S / L;
    out[g] = (val > 0.f) ? val : (__expf(val) - 1.f);
}

extern "C" void kernel_launch(void* const* d_in, const int* in_sizes, int n_in,
                              void* d_out, int out_size, void* d_ws, size_t ws_size,
                              hipStream_t stream) {
    const float* h   = (const float*)d_in[0];
    const int*   adj = (const int*)d_in[1];
    const float* W   = (const float*)d_in[2];
    const float* a   = (const float*)d_in[3];
    float* out = (float*)d_out;

    float* ws   = (float*)d_ws;
    float* Wh1  = ws;                                // 2048*32 = 65536
    float* Wh2T = Wh1 + N_NODES * OUT_F;             // 65536
    float* Q    = Wh2T + N_NODES * OUT_F;            // 2048
    float* C    = Q + N_NODES;                       // 32 (+pad to 64)
    float* m_ws = C + 64;                            // 2048*16
    float* l_ws = m_ws + (size_t)N_NODES * KB;       // 2048*16
    float* o_ws = l_ws + (size_t)N_NODES * KB;       // 2048*16*32 (4 MB)

    precompute_wh<<<N_NODES / 8, 256, 0, stream>>>(h, W, a, Wh1, Wh2T, Q, C);
    gat_partial<<<(N_NODES / TI) * KB / 4, 256, 0, stream>>>(Wh1, Wh2T, Q, C,
                                                             adj, m_ws, l_ws, o_ws);
    gat_combine<<<(N_NODES * OUT_F) / 256, 256, 0, stream>>>(m_ws, l_ws, o_ws, out);
}

// Round 9
// 115.813 us; speedup vs baseline: 1.1451x; 1.1451x over previous
//
#include <hip/hip_runtime.h>
#include <math.h>

#define N_NODES 2048
#define IN_F 128
#define OUT_F 32
#define NEG_INF -9e15f
#define KB 16      // k-chunks (split-k factor)
#define KC 128     // k per chunk
#define TI 8       // i rows per wave

// Swizzled column for the per-wave p buffer p_s[i][KC]: element k lives at
// column k ^ (((k>>4)&7)<<2). Conflict-free for both the phase-2 float2
// writes (k=2*lane) and phase-3 float4 broadcast reads (k=16*cp+4g).
__device__ __forceinline__ int pcol(int k) {
    return k ^ (((k >> 4) & 7) << 2);
}

// ---------------------------------------------------------------------------
// Kernel A: Wh1[N][32] = h @ W[:128], Wh2T[32][N] = (h @ W[128:])^T,
//           Q[k] = 0.6*sum_f a[f]*Wh2[k,f], C[f] = 0.4*a[f].
// (leakyrelu(x) = 0.6x + 0.4|x|; the per-row-i constant cancels in softmax.)
// ---------------------------------------------------------------------------
__global__ __launch_bounds__(256) void precompute_wh(
    const float* __restrict__ h, const float* __restrict__ W,
    const float* __restrict__ a,
    float* __restrict__ Wh1, float* __restrict__ Wh2T,
    float* __restrict__ Q, float* __restrict__ C)
{
    __shared__ float h_s[8][IN_F];
    __shared__ float tr[8][OUT_F];
    const int t = threadIdx.x;
    const int i0 = blockIdx.x * 8;

    ((float4*)&h_s[0][0])[t] = ((const float4*)(h + (size_t)i0 * IN_F))[t];
    __syncthreads();

    const int f = t & 31;
    const int r = t >> 5;
    float acc1 = 0.f, acc2 = 0.f;
    #pragma unroll 8
    for (int c = 0; c < IN_F; ++c) {
        const float hv = h_s[r][c];
        acc1 = fmaf(hv, W[c * OUT_F + f], acc1);
        acc2 = fmaf(hv, W[(IN_F + c) * OUT_F + f], acc2);
    }
    Wh1[(i0 + r) * OUT_F + f] = acc1;
    tr[r][f] = acc2;

    float q = 0.6f * a[f] * acc2;
    #pragma unroll
    for (int off = 16; off > 0; off >>= 1) q += __shfl_xor(q, off, 64);
    if (f == 0) Q[i0 + r] = q;
    if (blockIdx.x == 0 && t < OUT_F) C[t] = 0.4f * a[t];

    __syncthreads();
    const int f2 = t >> 3, r2 = t & 7;
    Wh2T[f2 * N_NODES + i0 + r2] = tr[r2][f2];
}

// ---------------------------------------------------------------------------
// Kernel B: 256-thread blocks = 4 INDEPENDENT waves; wave w of block b owns
// (i-tile = b>>2, k-chunk = (b&3)*4 + w). No __syncthreads anywhere: each
// wave uses its own LDS slice; within-wave LDS write->read ordering is
// enforced by lgkmcnt waits. Packs 4 waves per WG slot (R6's 4096
// single-wave WGs sat at ~3 waves/CU: WG-slot limited).
//   s[i,k] = Q[k] + sum_f C[f]*|Wh1[i,f]+Wh2[k,f]|, masked by adj.
//   Writes per chunk: m_c[i], l_c[i], o_c[i][32] (online-softmax partials).
// REGISTER RULE (R4/R5/R7 post-mortems): __launch_bounds__ min-waves arg
// caps VGPRs at 256/min; working set is ~164 VGPRs, so ANY min>=2 spills
// (R7: cap 128 -> 129 MB scratch traffic). No min arg: compiler picks ~164,
// VGPR pool then gives 3 waves/SIMD = 12 waves/CU = 3 blocks/CU.
// ---------------------------------------------------------------------------
__global__ __launch_bounds__(256) void gat_partial(
    const float* __restrict__ Wh1, const float* __restrict__ Wh2T,
    const float* __restrict__ Q, const float* __restrict__ C,
    const int* __restrict__ adj,
    float* __restrict__ m_ws, float* __restrict__ l_ws,
    float* __restrict__ o_ws)
{
    __shared__ __align__(16) float w1s_a[4][TI * OUT_F];   // 4 KB (1 KB/wave)
    __shared__ __align__(16) float p_s_a[4][TI * KC];      // 16 KB (4 KB/wave)

    const int t = threadIdx.x;
    const int lane = t & 63;
    const int wid = t >> 6;
    const int ib = blockIdx.x >> 2;
    const int cb = ((blockIdx.x & 3) << 2) | wid;
    const int i0 = ib * TI;
    const int kg = cb * KC + 2 * lane;               // global k of this pair

    float* __restrict__ w1s = w1s_a[wid];
    float* __restrict__ p_s = p_s_a[wid];

    // per-wave copy of the 8 Wh1 rows (64 lanes x float4 = exactly 1 KB)
    ((float4*)w1s)[lane] = ((const float4*)(Wh1 + (size_t)i0 * OUT_F))[lane];

    // prefetch adj + Q (HBM/L2 latency hides under the whole f-loop)
    int2 ad[TI];
    #pragma unroll
    for (int i = 0; i < TI; ++i)
        ad[i] = *(const int2*)(adj + (size_t)(i0 + i) * N_NODES + kg);
    const float2 q2 = *(const float2*)(Q + kg);

    // ---------------- Phase 1: scores ----------------
    float a0[TI], a1[TI];
    #pragma unroll
    for (int i = 0; i < TI; ++i) { a0[i] = 0.f; a1[i] = 0.f; }

    #pragma unroll
    for (int j = 0; j < 8; ++j) {
        float2 w2[4];
        #pragma unroll
        for (int e = 0; e < 4; ++e)
            w2[e] = *(const float2*)(Wh2T + (size_t)(4 * j + e) * N_NODES + kg);
        const float c0 = C[4 * j + 0], c1 = C[4 * j + 1];
        const float c2 = C[4 * j + 2], c3 = C[4 * j + 3];
        #pragma unroll
        for (int i = 0; i < TI; ++i) {
            const float4 w1 = *(const float4*)&w1s[i * OUT_F + 4 * j]; // LDS bcast
            float x;
            x = w1.x + w2[0].x; a0[i] = fmaf(c0, fabsf(x), a0[i]);
            x = w1.x + w2[0].y; a1[i] = fmaf(c0, fabsf(x), a1[i]);
            x = w1.y + w2[1].x; a0[i] = fmaf(c1, fabsf(x), a0[i]);
            x = w1.y + w2[1].y; a1[i] = fmaf(c1, fabsf(x), a1[i]);
            x = w1.z + w2[2].x; a0[i] = fmaf(c2, fabsf(x), a0[i]);
            x = w1.z + w2[2].y; a1[i] = fmaf(c2, fabsf(x), a1[i]);
            x = w1.w + w2[3].x; a0[i] = fmaf(c3, fabsf(x), a0[i]);
            x = w1.w + w2[3].y; a1[i] = fmaf(c3, fabsf(x), a1[i]);
        }
    }

    // ---------------- Phase 2: mask, local max, exp, local sum ----------------
    #pragma unroll
    for (int i = 0; i < TI; ++i) {
        const float s0 = (ad[i].x > 0) ? a0[i] + q2.x : NEG_INF;
        const float s1 = (ad[i].y > 0) ? a1[i] + q2.y : NEG_INF;
        float mm = fmaxf(s0, s1);
        #pragma unroll
        for (int off = 32; off > 0; off >>= 1)
            mm = fmaxf(mm, __shfl_xor(mm, off, 64));
        // gate masked entries: if the whole chunk is masked (mm == NEG_INF),
        // exp(s-mm) would be 1 — force p = 0 instead.
        const float p0 = (s0 > 0.5f * NEG_INF) ? __expf(s0 - mm) : 0.f;
        const float p1 = (s1 > 0.5f * NEG_INF) ? __expf(s1 - mm) : 0.f;
        float ll = p0 + p1;
        #pragma unroll
        for (int off = 32; off > 0; off >>= 1)
            ll += __shfl_xor(ll, off, 64);
        *(float2*)&p_s[i * KC + pcol(2 * lane)] = make_float2(p0, p1);
        if (lane == 0) {
            m_ws[(size_t)(i0 + i) * KB + cb] = mm;
            l_ws[(size_t)(i0 + i) * KB + cb] = ll;
        }
    }
    // no barrier: this wave wrote p_s and reads it back itself (lgkmcnt order)

    // ---------------- Phase 3: o_c = p @ Wh1 (chunk) ----------------
    const int fq = (lane & 7) * 4;   // f quad
    const int cp = lane >> 3;        // 8 sub-chunks of 16 k
    float4 av[TI];
    #pragma unroll
    for (int i = 0; i < TI; ++i) av[i] = make_float4(0.f, 0.f, 0.f, 0.f);

    #pragma unroll
    for (int g = 0; g < 4; ++g) {
        const int kl = 16 * cp + 4 * g;              // local k quad base
        float4 w[4];
        #pragma unroll
        for (int d = 0; d < 4; ++d)
            w[d] = *(const float4*)(Wh1 + (size_t)(cb * KC + kl + d) * OUT_F + fq);
        #pragma unroll
        for (int i = 0; i < TI; ++i) {
            const float4 pv = *(const float4*)&p_s[i * KC + pcol(kl)];
            av[i].x = fmaf(pv.x, w[0].x, av[i].x); av[i].y = fmaf(pv.x, w[0].y, av[i].y);
            av[i].z = fmaf(pv.x, w[0].z, av[i].z); av[i].w = fmaf(pv.x, w[0].w, av[i].w);
            av[i].x = fmaf(pv.y, w[1].x, av[i].x); av[i].y = fmaf(pv.y, w[1].y, av[i].y);
            av[i].z = fmaf(pv.y, w[1].z, av[i].z); av[i].w = fmaf(pv.y, w[1].w, av[i].w);
            av[i].x = fmaf(pv.z, w[2].x, av[i].x); av[i].y = fmaf(pv.z, w[2].y, av[i].y);
            av[i].z = fmaf(pv.z, w[2].z, av[i].z); av[i].w = fmaf(pv.z, w[2].w, av[i].w);
            av[i].x = fmaf(pv.w, w[3].x, av[i].x); av[i].y = fmaf(pv.w, w[3].y, av[i].y);
            av[i].z = fmaf(pv.w, w[3].z, av[i].z); av[i].w = fmaf(pv.w, w[3].w, av[i].w);
        }
    }

    // reduce over cp (lane bits 3-5)
    #pragma unroll
    for (int off = 8; off <= 32; off <<= 1) {
        #pragma unroll
        for (int i = 0; i < TI; ++i) {
            av[i].x += __shfl_xor(av[i].x, off, 64);
            av[i].y += __shfl_xor(av[i].y, off, 64);
            av[i].z += __shfl_xor(av[i].z, off, 64);
            av[i].w += __shfl_xor(av[i].w, off, 64);
        }
    }
    if (lane < 8) {                  // lane b writes f-quad 4b
        #pragma unroll
        for (int i = 0; i < TI; ++i)
            *(float4*)&o_ws[((size_t)(i0 + i) * KB + cb) * OUT_F + fq] = av[i];
    }
}

// ---------------------------------------------------------------------------
// Kernel C: combine the KB chunk partials per row:
//   M = max_c m_c;  w_c = e^{m_c - M};  L = sum_c l_c w_c;
//   out[i,f] = ELU( (sum_c o_c[i,f] w_c) / L ).
// Empty chunks: l_c = 0, m_c = NEG_INF -> w_c = 0.
// ---------------------------------------------------------------------------
__global__ __launch_bounds__(256) void gat_combine(
    const float* __restrict__ m_ws, const float* __restrict__ l_ws,
    const float* __restrict__ o_ws, float* __restrict__ out)
{
    const int g = blockIdx.x * 256 + threadIdx.x;    // 65536 = 2048*32
    const int i = g >> 5, f = g & 31;

    float mv[KB];
    float M = NEG_INF;
    #pragma unroll
    for (int c = 0; c < KB; ++c) {
        mv[c] = m_ws[(size_t)i * KB + c];
        M = fmaxf(M, mv[c]);
    }
    float L = 0.f, S = 0.f;
    #pragma unroll
    for (int c = 0; c < KB; ++c) {
        const float wc = __expf(mv[c] - M);
        L = fmaf(l_ws[(size_t)i * KB + c], wc, L);
        S = fmaf(o_ws[((size_t)i * KB + c) * OUT_F + f], wc, S);
    }
    const float val = S / L;
    out[g] = (val > 0.f) ? val : (__expf(val) - 1.f);
}

extern "C" void kernel_launch(void* const* d_in, const int* in_sizes, int n_in,
                              void* d_out, int out_size, void* d_ws, size_t ws_size,
                              hipStream_t stream) {
    const float* h   = (const float*)d_in[0];
    const int*   adj = (const int*)d_in[1];
    const float* W   = (const float*)d_in[2];
    const float* a   = (const float*)d_in[3];
    float* out = (float*)d_out;

    float* ws   = (float*)d_ws;
    float* Wh1  = ws;                                // 2048*32 = 65536
    float* Wh2T = Wh1 + N_NODES * OUT_F;             // 65536
    float* Q    = Wh2T + N_NODES * OUT_F;            // 2048
    float* C    = Q + N_NODES;                       // 32 (+pad to 64)
    float* m_ws = C + 64;                            // 2048*16
    float* l_ws = m_ws + (size_t)N_NODES * KB;       // 2048*16
    float* o_ws = l_ws + (size_t)N_NODES * KB;       // 2048*16*32 (4 MB)

    precompute_wh<<<N_NODES / 8, 256, 0, stream>>>(h, W, a, Wh1, Wh2T, Q, C);
    gat_partial<<<(N_NODES / TI) * KB / 4, 256, 0, stream>>>(Wh1, Wh2T, Q, C,
                                                             adj, m_ws, l_ws, o_ws);
    gat_combine<<<(N_NODES * OUT_F) / 256, 256, 0, stream>>>(m_ws, l_ws, o_ws, out);
}